// Round 1
// baseline (958.297 us; speedup 1.0000x reference)
//
#include <hip/hip_runtime.h>

typedef __bf16 bf16x8 __attribute__((ext_vector_type(8)));
typedef float  f32x4  __attribute__((ext_vector_type(4)));

#define D_DIM 9984   // 13*768
#define H1P   1024   // H1=1000 padded
#define M_DIM 8192   // B*S

__device__ __forceinline__ void gld_lds16(const void* g, void* l) {
  __builtin_amdgcn_global_load_lds((__attribute__((address_space(1))) void*)(g),
                                   (__attribute__((address_space(3))) void*)(l),
                                   16, 0, 0);
}

// ---- W1 [9984][1000] fp32 -> W1T [1024][9984] bf16 (rows >=1000 zeroed) ----
__global__ __launch_bounds__(256) void k_transpose_w1(const float* __restrict__ W1,
                                                      __bf16* __restrict__ W1T) {
  __shared__ float tile[32][33];
  const int bk = blockIdx.x, bn = blockIdx.y;
  const int tx = threadIdx.x, ty = threadIdx.y;
#pragma unroll
  for (int i = 0; i < 4; ++i) {
    const int kk = bk * 32 + ty + i * 8;
    const int nn = bn * 32 + tx;
    tile[ty + i * 8][tx] = (nn < 1000) ? W1[(size_t)kk * 1000 + nn] : 0.f;
  }
  __syncthreads();
#pragma unroll
  for (int i = 0; i < 4; ++i) {
    const int nn = bn * 32 + ty + i * 8;   // row of W1T (n)
    const int kk = bk * 32 + tx;           // col of W1T (k)
    W1T[(size_t)nn * D_DIM + kk] = (__bf16)tile[tx][ty + i * 8];
  }
}

// ---- W2 [1000][40] fp32 -> W2T [64][1024] bf16 (pads zeroed) ----
__global__ void k_prep_w2(const float* __restrict__ W2, __bf16* __restrict__ W2T) {
  const int idx = blockIdx.x * 256 + threadIdx.x;  // 65536 total
  const int j = idx >> 10, k = idx & 1023;
  const float v = (j < 40 && k < 1000) ? W2[k * 40 + j] : 0.f;
  W2T[idx] = (__bf16)v;
}

// ---- GEMM1: h1[8192][1024]bf16 = relu( A[8192][9984]f32 @ W1 + b1 ) ----
// 128x128 tile, BK=32, 4 waves (2x2), 4x4 MFMA frags per wave.
// A: fp32 global -> regs (prefetched) -> cvt bf16 -> ds_write_b128
// B: W1T bf16 via global_load_lds width 16
__global__ __launch_bounds__(256) void k_gemm1(const float* __restrict__ A,
                                               const __bf16* __restrict__ BT,
                                               const float* __restrict__ b1,
                                               __bf16* __restrict__ C) {
  __shared__ __bf16 As[128 * 32];
  __shared__ __bf16 Bs[128 * 32];
  const int tid  = threadIdx.x;
  const int lane = tid & 63;
  const int wid  = tid >> 6;
  const int tn = blockIdx.x, tm = blockIdx.y;
  const int wm = wid & 1, wn = wid >> 1;

  // A staging: thread -> (row = tid/2, 16-float half = tid%2)
  const int arow = tid >> 1;
  const int acol = (tid & 1) * 16;
  const float* ag = A + (size_t)(tm * 128 + arow) * D_DIM + acol;
  __bf16* asw = &As[arow * 32 + acol];

  // B staging: chunk c covers 16 rows of Bs; wave w handles chunks 2w, 2w+1
  const int c0 = wid * 2, c1 = wid * 2 + 1;
  const __bf16* bg0 = BT + (size_t)(tn * 128 + c0 * 16 + (lane >> 2)) * D_DIM + (lane & 3) * 8;
  const __bf16* bg1 = BT + (size_t)(tn * 128 + c1 * 16 + (lane >> 2)) * D_DIM + (lane & 3) * 8;
  __bf16* bl0 = &Bs[c0 * 16 * 32];  // wave-uniform LDS base
  __bf16* bl1 = &Bs[c1 * 16 * 32];

  const int fr = lane & 15;
  const int kq = (lane >> 4) * 8;

  f32x4 acc[4][4] = {};

  float4 pa[4];
  {
    const float4* ap = (const float4*)ag;
    pa[0] = ap[0]; pa[1] = ap[1]; pa[2] = ap[2]; pa[3] = ap[3];
  }

  for (int i = 0; i < 312; ++i) {
    const int k0 = i * 32;
    __syncthreads();                 // prev compute done; LDS reusable
    {                                // cvt + write A tile
      const float* pf = (const float*)pa;
      bf16x8 w0, w1;
#pragma unroll
      for (int j = 0; j < 8; ++j) { w0[j] = (__bf16)pf[j]; w1[j] = (__bf16)pf[j + 8]; }
      *(bf16x8*)asw       = w0;
      *(bf16x8*)(asw + 8) = w1;
    }
    gld_lds16(bg0 + k0, bl0);        // async B -> LDS
    gld_lds16(bg1 + k0, bl1);
    __syncthreads();                 // drains vmcnt: Bs + As ready
    if (i != 311) {                  // prefetch next A, latency hides under MFMA
      const float4* ap = (const float4*)(ag + k0 + 32);
      pa[0] = ap[0]; pa[1] = ap[1]; pa[2] = ap[2]; pa[3] = ap[3];
    }
    bf16x8 af[4], bf[4];
#pragma unroll
    for (int mi = 0; mi < 4; ++mi)
      af[mi] = *(const bf16x8*)&As[(wm * 64 + mi * 16 + fr) * 32 + kq];
#pragma unroll
    for (int ni = 0; ni < 4; ++ni)
      bf[ni] = *(const bf16x8*)&Bs[(wn * 64 + ni * 16 + fr) * 32 + kq];
#pragma unroll
    for (int mi = 0; mi < 4; ++mi)
#pragma unroll
      for (int ni = 0; ni < 4; ++ni)
        acc[mi][ni] = __builtin_amdgcn_mfma_f32_16x16x32_bf16(af[mi], bf[ni], acc[mi][ni], 0, 0, 0);
  }

  // epilogue: D layout col=lane&15, row=(lane>>4)*4+reg  [measured m89]
  const int row0 = tm * 128 + wm * 64 + ((lane >> 4) << 2);
  const int col0 = tn * 128 + wn * 64 + fr;
#pragma unroll
  for (int ni = 0; ni < 4; ++ni) {
    const int col = col0 + ni * 16;
    const float bias = (col < 1000) ? b1[col] : 0.f;
#pragma unroll
    for (int mi = 0; mi < 4; ++mi)
#pragma unroll
      for (int r = 0; r < 4; ++r) {
        const float v = acc[mi][ni][r] + bias;
        C[(size_t)(row0 + mi * 16 + r) * H1P + col] = (__bf16)fmaxf(v, 0.f);
      }
  }
}

// ---- GEMM2: h2[8192][64]f32 = relu( h1 @ W2 + b2 ), K=1024, N=64(pad) ----
__global__ __launch_bounds__(256) void k_gemm2(const __bf16* __restrict__ h1,
                                               const __bf16* __restrict__ W2T,
                                               const float* __restrict__ b2,
                                               float* __restrict__ h2) {
  __shared__ __bf16 As[64 * 32];
  __shared__ __bf16 Bs[64 * 32];
  const int tid  = threadIdx.x;
  const int lane = tid & 63;
  const int wid  = tid >> 6;
  const int bm   = blockIdx.x;

  const __bf16* ag = h1  + (size_t)(bm * 64 + wid * 16 + (lane >> 2)) * H1P + (lane & 3) * 8;
  const __bf16* bg = W2T + (size_t)(wid * 16 + (lane >> 2)) * H1P + (lane & 3) * 8;
  __bf16* al = &As[wid * 16 * 32];
  __bf16* bl = &Bs[wid * 16 * 32];

  const int fr = lane & 15;
  const int kq = (lane >> 4) * 8;
  f32x4 acc[4] = {};

  for (int i = 0; i < 32; ++i) {
    const int k0 = i * 32;
    __syncthreads();
    gld_lds16(ag + k0, al);
    gld_lds16(bg + k0, bl);
    __syncthreads();
    const bf16x8 a = *(const bf16x8*)&As[(wid * 16 + fr) * 32 + kq];
#pragma unroll
    for (int ni = 0; ni < 4; ++ni) {
      const bf16x8 b = *(const bf16x8*)&Bs[(ni * 16 + fr) * 32 + kq];
      acc[ni] = __builtin_amdgcn_mfma_f32_16x16x32_bf16(a, b, acc[ni], 0, 0, 0);
    }
  }
  const int m0 = bm * 64 + wid * 16 + ((lane >> 4) << 2);
#pragma unroll
  for (int ni = 0; ni < 4; ++ni) {
    const int j = ni * 16 + fr;
    const float bias = (j < 40) ? b2[j] : 0.f;
#pragma unroll
    for (int r = 0; r < 4; ++r)
      h2[(size_t)(m0 + r) * 64 + j] = fmaxf(acc[ni][r] + bias, 0.f);
  }
}

// ---- logits[8192] = sigmoid( h2[:, :40] @ W3 + b3 ) ----
__global__ void k_logits(const float* __restrict__ h2, const float* __restrict__ W3,
                         const float* __restrict__ b3, float* __restrict__ lg) {
  const int r = blockIdx.x * 256 + threadIdx.x;
  const float4* h = (const float4*)(h2 + (size_t)r * 64);
  const float4* w = (const float4*)W3;
  float s = b3[0];
#pragma unroll
  for (int j = 0; j < 10; ++j) {
    const float4 a = h[j], b = w[j];
    s += a.x * b.x + a.y * b.y + a.z * b.z + a.w * b.w;
  }
  lg[r] = 1.f / (1.f + __expf(-s));
}

// ---- ragged gather ----
__global__ void k_gather(const int* __restrict__ ts, const float* __restrict__ lg,
                         float* __restrict__ out) {
  const int t = blockIdx.x * 256 + threadIdx.x;
  const int b = t >> 9;
  const int s = ts[t];
  out[t] = (s > 0 && s < 512) ? lg[(b << 9) + s] : 0.f;
}

extern "C" void kernel_launch(void* const* d_in, const int* in_sizes, int n_in,
                              void* d_out, int out_size, void* d_ws, size_t ws_size,
                              hipStream_t stream) {
  const float* hs = (const float*)d_in[0];
  const int*   ts = (const int*)d_in[1];
  const float* W1 = (const float*)d_in[2];
  const float* b1 = (const float*)d_in[3];
  const float* W2 = (const float*)d_in[4];
  const float* b2 = (const float*)d_in[5];
  const float* W3 = (const float*)d_in[6];
  const float* b3 = (const float*)d_in[7];
  float* out = (float*)d_out;

  char* ws = (char*)d_ws;
  __bf16* W1T = (__bf16*)(ws);                                   // 1024*9984*2 = 20,447,232
  __bf16* h1  = (__bf16*)(ws + 20447232);                        // 8192*1024*2 = 16,777,216
  __bf16* W2T = (__bf16*)(ws + 20447232 + 16777216);             // 64*1024*2  =    131,072
  float*  h2  = (float*) (ws + 20447232 + 16777216 + 131072);    // 8192*64*4  =  2,097,152
  float*  lg  = (float*) (ws + 20447232 + 16777216 + 131072 + 2097152);  // 8192*4
  // total ~39.5 MB

  k_transpose_w1<<<dim3(312, 32), dim3(32, 8), 0, stream>>>(W1, W1T);
  k_prep_w2<<<256, 256, 0, stream>>>(W2, W2T);
  k_gemm1<<<dim3(8, 64), 256, 0, stream>>>(hs, W1T, b1, h1);
  k_gemm2<<<128, 256, 0, stream>>>(h1, W2T, b2, h2);
  k_logits<<<32, 256, 0, stream>>>(h2, W3, b3, lg);
  k_gather<<<32, 256, 0, stream>>>(ts, lg, out);
}

// Round 2
// 726.845 us; speedup vs baseline: 1.3184x; 1.3184x over previous
//
#include <hip/hip_runtime.h>

typedef __bf16 bf16x8 __attribute__((ext_vector_type(8)));
typedef float  f32x4  __attribute__((ext_vector_type(4)));

#define D_DIM 9984   // 13*768
#define H1P   1024   // H1=1000 padded
#define M_DIM 8192   // B*S

__device__ __forceinline__ void gld_lds16(const void* g, void* l) {
  __builtin_amdgcn_global_load_lds((__attribute__((address_space(1))) void*)(g),
                                   (__attribute__((address_space(3))) void*)(l),
                                   16, 0, 0);
}

// ---- A [8192][9984] fp32 -> bf16 ----
__global__ __launch_bounds__(256) void k_cvt_a(const float* __restrict__ A,
                                               __bf16* __restrict__ Ab) {
  const size_t t = (size_t)blockIdx.x * 256 + threadIdx.x;   // 10,223,616 threads
  const float4* p = (const float4*)A + t * 2;
  const float4 a = p[0], b = p[1];
  bf16x8 o;
  o[0] = (__bf16)a.x; o[1] = (__bf16)a.y; o[2] = (__bf16)a.z; o[3] = (__bf16)a.w;
  o[4] = (__bf16)b.x; o[5] = (__bf16)b.y; o[6] = (__bf16)b.z; o[7] = (__bf16)b.w;
  *(bf16x8*)(Ab + t * 8) = o;
}

// ---- W1 [9984][1000] fp32 -> W1T [1024][9984] bf16 (rows >=1000 zeroed) ----
__global__ __launch_bounds__(256) void k_transpose_w1(const float* __restrict__ W1,
                                                      __bf16* __restrict__ W1T) {
  __shared__ float tile[32][33];
  const int bk = blockIdx.x, bn = blockIdx.y;
  const int tx = threadIdx.x, ty = threadIdx.y;
#pragma unroll
  for (int i = 0; i < 4; ++i) {
    const int kk = bk * 32 + ty + i * 8;
    const int nn = bn * 32 + tx;
    tile[ty + i * 8][tx] = (nn < 1000) ? W1[(size_t)kk * 1000 + nn] : 0.f;
  }
  __syncthreads();
#pragma unroll
  for (int i = 0; i < 4; ++i) {
    const int nn = bn * 32 + ty + i * 8;   // row of W1T (n)
    const int kk = bk * 32 + tx;           // col of W1T (k)
    W1T[(size_t)nn * D_DIM + kk] = (__bf16)tile[tx][ty + i * 8];
  }
}

// ---- W2 [1000][40] fp32 -> W2T [64][1024] bf16 (pads zeroed) ----
__global__ void k_prep_w2(const float* __restrict__ W2, __bf16* __restrict__ W2T) {
  const int idx = blockIdx.x * 256 + threadIdx.x;  // 65536 total
  const int j = idx >> 10, k = idx & 1023;
  const float v = (j < 40 && k < 1000) ? W2[k * 40 + j] : 0.f;
  W2T[idx] = (__bf16)v;
}

// ---- GEMM1 (bf16 A): h1 = relu(A @ W1 + b1), m97 shape ----
// 128x128 tile, BK=32, 4 waves 2x2, 4x4 frags; both operands via global_load_lds.
__global__ __launch_bounds__(256) void k_gemm1b(const __bf16* __restrict__ A,
                                                const __bf16* __restrict__ BT,
                                                const float* __restrict__ b1,
                                                __bf16* __restrict__ C) {
  __shared__ __bf16 As[128 * 32];
  __shared__ __bf16 Bs[128 * 32];
  const int tid  = threadIdx.x;
  const int lane = tid & 63;
  const int wid  = tid >> 6;
  const int tm = blockIdx.x, tn = blockIdx.y;   // id = tn*64+tm -> same-tm blocks share XCD
  const int wm = wid & 1, wn = wid >> 1;

  // staging: 8 chunks of 16 rows per matrix; wave w does chunks 2w, 2w+1
  const int c0 = wid * 2, c1 = c0 + 1;
  const int lr = lane >> 2;            // 16 rows per chunk
  const int lc = (lane & 3) * 8;       // 4 x 8 bf16 = 32 cols
  const __bf16* ag0 = A  + (size_t)(tm * 128 + c0 * 16 + lr) * D_DIM + lc;
  const __bf16* ag1 = A  + (size_t)(tm * 128 + c1 * 16 + lr) * D_DIM + lc;
  const __bf16* bg0 = BT + (size_t)(tn * 128 + c0 * 16 + lr) * D_DIM + lc;
  const __bf16* bg1 = BT + (size_t)(tn * 128 + c1 * 16 + lr) * D_DIM + lc;
  __bf16* al0 = &As[c0 * 16 * 32];
  __bf16* al1 = &As[c1 * 16 * 32];
  __bf16* bl0 = &Bs[c0 * 16 * 32];
  __bf16* bl1 = &Bs[c1 * 16 * 32];

  const int fr = lane & 15;
  const int kq = (lane >> 4) * 8;
  f32x4 acc[4][4] = {};

  for (int i = 0; i < 312; ++i) {
    const size_t k0 = (size_t)i * 32;
    __syncthreads();
    gld_lds16(ag0 + k0, al0);
    gld_lds16(ag1 + k0, al1);
    gld_lds16(bg0 + k0, bl0);
    gld_lds16(bg1 + k0, bl1);
    __syncthreads();
    bf16x8 af[4], bf[4];
#pragma unroll
    for (int mi = 0; mi < 4; ++mi)
      af[mi] = *(const bf16x8*)&As[(wm * 64 + mi * 16 + fr) * 32 + kq];
#pragma unroll
    for (int ni = 0; ni < 4; ++ni)
      bf[ni] = *(const bf16x8*)&Bs[(wn * 64 + ni * 16 + fr) * 32 + kq];
#pragma unroll
    for (int mi = 0; mi < 4; ++mi)
#pragma unroll
      for (int ni = 0; ni < 4; ++ni)
        acc[mi][ni] = __builtin_amdgcn_mfma_f32_16x16x32_bf16(af[mi], bf[ni], acc[mi][ni], 0, 0, 0);
  }

  // D layout: col=lane&15, row=(lane>>4)*4+reg  [m89]
  const int row0 = tm * 128 + wm * 64 + ((lane >> 4) << 2);
  const int col0 = tn * 128 + wn * 64 + fr;
#pragma unroll
  for (int ni = 0; ni < 4; ++ni) {
    const int col = col0 + ni * 16;
    const float bias = (col < 1000) ? b1[col] : 0.f;
#pragma unroll
    for (int mi = 0; mi < 4; ++mi)
#pragma unroll
      for (int r = 0; r < 4; ++r) {
        const float v = acc[mi][ni][r] + bias;
        C[(size_t)(row0 + mi * 16 + r) * H1P + col] = (__bf16)fmaxf(v, 0.f);
      }
  }
}

// ---- Fallback GEMM1 (fp32 A, in-kernel cvt) — used only if ws too small ----
__global__ __launch_bounds__(256) void k_gemm1(const float* __restrict__ A,
                                               const __bf16* __restrict__ BT,
                                               const float* __restrict__ b1,
                                               __bf16* __restrict__ C) {
  __shared__ __bf16 As[128 * 32];
  __shared__ __bf16 Bs[128 * 32];
  const int tid  = threadIdx.x;
  const int lane = tid & 63;
  const int wid  = tid >> 6;
  const int tm = blockIdx.x, tn = blockIdx.y;
  const int wm = wid & 1, wn = wid >> 1;

  const int arow = tid >> 1;
  const int acol = (tid & 1) * 16;
  const float* ag = A + (size_t)(tm * 128 + arow) * D_DIM + acol;
  __bf16* asw = &As[arow * 32 + acol];

  const int c0 = wid * 2, c1 = wid * 2 + 1;
  const __bf16* bg0 = BT + (size_t)(tn * 128 + c0 * 16 + (lane >> 2)) * D_DIM + (lane & 3) * 8;
  const __bf16* bg1 = BT + (size_t)(tn * 128 + c1 * 16 + (lane >> 2)) * D_DIM + (lane & 3) * 8;
  __bf16* bl0 = &Bs[c0 * 16 * 32];
  __bf16* bl1 = &Bs[c1 * 16 * 32];

  const int fr = lane & 15;
  const int kq = (lane >> 4) * 8;
  f32x4 acc[4][4] = {};

  float4 pa[4];
  {
    const float4* ap = (const float4*)ag;
    pa[0] = ap[0]; pa[1] = ap[1]; pa[2] = ap[2]; pa[3] = ap[3];
  }
  for (int i = 0; i < 312; ++i) {
    const int k0 = i * 32;
    __syncthreads();
    {
      const float* pf = (const float*)pa;
      bf16x8 w0, w1;
#pragma unroll
      for (int j = 0; j < 8; ++j) { w0[j] = (__bf16)pf[j]; w1[j] = (__bf16)pf[j + 8]; }
      *(bf16x8*)asw       = w0;
      *(bf16x8*)(asw + 8) = w1;
    }
    gld_lds16(bg0 + k0, bl0);
    gld_lds16(bg1 + k0, bl1);
    __syncthreads();
    if (i != 311) {
      const float4* ap = (const float4*)(ag + k0 + 32);
      pa[0] = ap[0]; pa[1] = ap[1]; pa[2] = ap[2]; pa[3] = ap[3];
    }
    bf16x8 af[4], bf[4];
#pragma unroll
    for (int mi = 0; mi < 4; ++mi)
      af[mi] = *(const bf16x8*)&As[(wm * 64 + mi * 16 + fr) * 32 + kq];
#pragma unroll
    for (int ni = 0; ni < 4; ++ni)
      bf[ni] = *(const bf16x8*)&Bs[(wn * 64 + ni * 16 + fr) * 32 + kq];
#pragma unroll
    for (int mi = 0; mi < 4; ++mi)
#pragma unroll
      for (int ni = 0; ni < 4; ++ni)
        acc[mi][ni] = __builtin_amdgcn_mfma_f32_16x16x32_bf16(af[mi], bf[ni], acc[mi][ni], 0, 0, 0);
  }
  const int row0 = tm * 128 + wm * 64 + ((lane >> 4) << 2);
  const int col0 = tn * 128 + wn * 64 + fr;
#pragma unroll
  for (int ni = 0; ni < 4; ++ni) {
    const int col = col0 + ni * 16;
    const float bias = (col < 1000) ? b1[col] : 0.f;
#pragma unroll
    for (int mi = 0; mi < 4; ++mi)
#pragma unroll
      for (int r = 0; r < 4; ++r) {
        const float v = acc[mi][ni][r] + bias;
        C[(size_t)(row0 + mi * 16 + r) * H1P + col] = (__bf16)fmaxf(v, 0.f);
      }
  }
}

// ---- GEMM2 + logits fused: lg[m] = sigmoid(relu(h1 @ W2 + b2) @ W3 + b3) ----
__global__ __launch_bounds__(256) void k_gemm2l(const __bf16* __restrict__ h1,
                                                const __bf16* __restrict__ W2T,
                                                const float* __restrict__ b2,
                                                const float* __restrict__ W3,
                                                const float* __restrict__ b3,
                                                float* __restrict__ lg) {
  __shared__ __bf16 As[64 * 32];
  __shared__ __bf16 Bs[64 * 32];
  const int tid  = threadIdx.x;
  const int lane = tid & 63;
  const int wid  = tid >> 6;
  const int bm   = blockIdx.x;

  const __bf16* ag = h1  + (size_t)(bm * 64 + wid * 16 + (lane >> 2)) * H1P + (lane & 3) * 8;
  const __bf16* bg = W2T + (size_t)(wid * 16 + (lane >> 2)) * H1P + (lane & 3) * 8;
  __bf16* al = &As[wid * 16 * 32];
  __bf16* bl = &Bs[wid * 16 * 32];

  const int fr = lane & 15;
  const int kq = (lane >> 4) * 8;
  f32x4 acc[4] = {};

  for (int i = 0; i < 32; ++i) {
    const int k0 = i * 32;
    __syncthreads();
    gld_lds16(ag + k0, al);
    gld_lds16(bg + k0, bl);
    __syncthreads();
    const bf16x8 a = *(const bf16x8*)&As[(wid * 16 + fr) * 32 + kq];
#pragma unroll
    for (int ni = 0; ni < 4; ++ni) {
      const bf16x8 b = *(const bf16x8*)&Bs[(ni * 16 + fr) * 32 + kq];
      acc[ni] = __builtin_amdgcn_mfma_f32_16x16x32_bf16(a, b, acc[ni], 0, 0, 0);
    }
  }
  // epilogue: lane holds j = ni*16+fr for rows m0..m0+3; reduce over j with W3
  float s[4] = {0.f, 0.f, 0.f, 0.f};
#pragma unroll
  for (int ni = 0; ni < 4; ++ni) {
    const int j = ni * 16 + fr;
    if (j < 40) {
      const float w3 = W3[j], bias = b2[j];
#pragma unroll
      for (int r = 0; r < 4; ++r)
        s[r] += fmaxf(acc[ni][r] + bias, 0.f) * w3;
    }
  }
#pragma unroll
  for (int off = 1; off < 16; off <<= 1)
#pragma unroll
    for (int r = 0; r < 4; ++r)
      s[r] += __shfl_xor(s[r], off, 16);
  if (fr == 0) {
    const int m0 = bm * 64 + wid * 16 + ((lane >> 4) << 2);
    const float b3v = b3[0];
#pragma unroll
    for (int r = 0; r < 4; ++r)
      lg[m0 + r] = 1.f / (1.f + __expf(-(s[r] + b3v)));
  }
}

// ---- ragged gather ----
__global__ void k_gather(const int* __restrict__ ts, const float* __restrict__ lg,
                         float* __restrict__ out) {
  const int t = blockIdx.x * 256 + threadIdx.x;
  const int b = t >> 9;
  const int s = ts[t];
  out[t] = (s > 0 && s < 512) ? lg[(b << 9) + s] : 0.f;
}

extern "C" void kernel_launch(void* const* d_in, const int* in_sizes, int n_in,
                              void* d_out, int out_size, void* d_ws, size_t ws_size,
                              hipStream_t stream) {
  const float* hs = (const float*)d_in[0];
  const int*   ts = (const int*)d_in[1];
  const float* W1 = (const float*)d_in[2];
  const float* b1 = (const float*)d_in[3];
  const float* W2 = (const float*)d_in[4];
  const float* b2 = (const float*)d_in[5];
  const float* W3 = (const float*)d_in[6];
  const float* b3 = (const float*)d_in[7];
  float* out = (float*)d_out;
  char* ws = (char*)d_ws;

  const size_t ABF = 163577856;        // 8192*9984*2
  const size_t NEED = ABF + 20447232 + 16777216 + 131072 + 32768;  // ~191.7 MiB

  if (ws_size >= NEED) {
    __bf16* Ab  = (__bf16*)(ws);
    __bf16* W1T = (__bf16*)(ws + ABF);
    __bf16* h1  = (__bf16*)(ws + ABF + 20447232);
    __bf16* W2T = (__bf16*)(ws + ABF + 20447232 + 16777216);
    float*  lg  = (float*) (ws + ABF + 20447232 + 16777216 + 131072);

    k_cvt_a<<<39936, 256, 0, stream>>>(hs, Ab);
    k_transpose_w1<<<dim3(312, 32), dim3(32, 8), 0, stream>>>(W1, W1T);
    k_prep_w2<<<256, 256, 0, stream>>>(W2, W2T);
    k_gemm1b<<<dim3(64, 8), 256, 0, stream>>>(Ab, W1T, b1, h1);
    k_gemm2l<<<128, 256, 0, stream>>>(h1, W2T, b2, W3, b3, lg);
    k_gather<<<32, 256, 0, stream>>>(ts, lg, out);
  } else {
    __bf16* W1T = (__bf16*)(ws);
    __bf16* h1  = (__bf16*)(ws + 20447232);
    __bf16* W2T = (__bf16*)(ws + 20447232 + 16777216);
    float*  lg  = (float*) (ws + 20447232 + 16777216 + 131072);

    k_transpose_w1<<<dim3(312, 32), dim3(32, 8), 0, stream>>>(W1, W1T);
    k_prep_w2<<<256, 256, 0, stream>>>(W2, W2T);
    k_gemm1<<<dim3(64, 8), 256, 0, stream>>>(hs, W1T, b1, h1);
    k_gemm2l<<<128, 256, 0, stream>>>(h1, W2T, b2, W3, b3, lg);
    k_gather<<<32, 256, 0, stream>>>(ts, lg, out);
  }
}